// Round 8
// baseline (166.180 us; speedup 1.0000x reference)
//
#include <hip/hip_runtime.h>
#include <hip/hip_cooperative_groups.h>
#include <math.h>

namespace cg = cooperative_groups;

#define N_S 1024
#define XD  768
#define LOW 300
#define KP  320     // f16 k-padding
#define KP2 160     // u32 (h2) per row
#define GRID 512

typedef _Float16 h2  __attribute__((ext_vector_type(2)));
typedef __fp16   g2  __attribute__((ext_vector_type(2)));
typedef _Float16 v8h __attribute__((ext_vector_type(8)));
typedef float    f4  __attribute__((ext_vector_type(4)));

union U32H2 { unsigned int u; h2 h; };
__device__ inline h2 u2h(unsigned int v){ U32H2 t; t.u = v; return t.h; }
__device__ inline unsigned int pk(float a, float b){
    g2 t = __builtin_amdgcn_cvt_pkrtz(a, b);
    return __builtin_bit_cast(unsigned int, t);
}
union U4V8 { uint4 u; v8h v; };

struct SmemG {                      // phase 1: 26112 B
    unsigned int As[2][32][34];     // [row][k/2] f16-pairs
    unsigned int Bs[2][64][34];     // [ncol][k/2]
};
struct SmemP {                      // phase 2: 13696 B
    unsigned int Hy[2][16][36];     // [kk][i]
    unsigned int Hx[2][16][66];     // [kk][j]
    unsigned int w2s[KP2];
};
union Smem { SmemG g; SmemP p; };

// ---------------------------------------------------------------------------
// Phase 1: projection GEMM via MFMA f16. Job = 32-row x 64-kcol tile.
//   which==0 : hx[j][k] = sum_m x[j,m]*W1[m,k]
//   which==1 : hy[i][k] = sum_m y[i,m]*W1[768+m,k] + b1[k]
// 256 thr = 4 waves (2M x 2N quadrants of 16M x 32N), K-step 64, dbuf.
// ---------------------------------------------------------------------------
__device__ void phase_gemm(Smem& sm, int job,
    const float* __restrict__ x, const float* __restrict__ y,
    const float* __restrict__ W1, const float* __restrict__ b1g,
    unsigned int* __restrict__ hx_h, unsigned int* __restrict__ hy_h)
{
    const int tid = threadIdx.x;
    const int which = job >= 160;
    const int t = which ? job - 160 : job;
    const int n0 = (t % 5) * 64;
    const int r0 = (t / 5) * 32;
    const float* A = which ? y : x;
    const float* W = W1 + (size_t)which * XD * LOW;
    _Float16* outh = (_Float16*)(which ? hy_h : hx_h);

    const int w = tid >> 6, l = tid & 63;
    const int wn = w & 1, wm = w >> 1;
    const int lr = l & 15, lg = l >> 4;

    const int arow = tid >> 3, aq = tid & 7;   // A staging: 32 rows x 8 groups
    const int bn = tid & 63, bms = tid >> 6;   // B staging: 64 ncols x 4 m-groups
    const bool bin = (n0 + bn) < LOW;

    f4 acc[2] = {};
    float4 a0, a1; float bw[16];
    a0 = *(const float4*)&A[(size_t)(r0 + arow) * XD + aq * 8];
    a1 = *(const float4*)&A[(size_t)(r0 + arow) * XD + aq * 8 + 4];
    #pragma unroll
    for (int s = 0; s < 16; ++s)
        bw[s] = bin ? W[(size_t)(bms * 16 + s) * LOW + n0 + bn] : 0.f;

    const int NC = XD / 64;                    // 12
    for (int c = 0; c < NC; ++c) {
        const int buf = c & 1;
        *(uint4*)&sm.g.As[buf][arow][aq * 4] =
            uint4{ pk(a0.x,a0.y), pk(a0.z,a0.w), pk(a1.x,a1.y), pk(a1.z,a1.w) };
        *(uint4*)&sm.g.Bs[buf][bn][bms * 8] =
            uint4{ pk(bw[0],bw[1]), pk(bw[2],bw[3]), pk(bw[4],bw[5]), pk(bw[6],bw[7]) };
        *(uint4*)&sm.g.Bs[buf][bn][bms * 8 + 4] =
            uint4{ pk(bw[8],bw[9]), pk(bw[10],bw[11]), pk(bw[12],bw[13]), pk(bw[14],bw[15]) };
        __syncthreads();
        if (c + 1 < NC) {
            const int kb = (c + 1) * 64;
            a0 = *(const float4*)&A[(size_t)(r0 + arow) * XD + kb + aq * 8];
            a1 = *(const float4*)&A[(size_t)(r0 + arow) * XD + kb + aq * 8 + 4];
            #pragma unroll
            for (int s = 0; s < 16; ++s)
                bw[s] = bin ? W[(size_t)(kb + bms * 16 + s) * LOW + n0 + bn] : 0.f;
        }
        #pragma unroll
        for (int ks = 0; ks < 2; ++ks) {
            const int ko = ks * 16 + lg * 4;
            U4V8 af; af.u = *(const uint4*)&sm.g.As[buf][wm * 16 + lr][ko];
            #pragma unroll
            for (int nt = 0; nt < 2; ++nt) {
                U4V8 bf; bf.u = *(const uint4*)&sm.g.Bs[buf][wn * 32 + nt * 16 + lr][ko];
                acc[nt] = __builtin_amdgcn_mfma_f32_16x16x32_f16(af.v, bf.v, acc[nt], 0, 0, 0);
            }
        }
    }

    // D: col = l&15, row = 4*(l>>4)+r  (m89-verified)
    #pragma unroll
    for (int nt = 0; nt < 2; ++nt) {
        const int col = n0 + wn * 32 + nt * 16 + lr;
        const float b1v = (which && col < LOW) ? b1g[col] : 0.f;
        #pragma unroll
        for (int r = 0; r < 4; ++r) {
            const int row = r0 + wm * 16 + lg * 4 + r;
            outh[(size_t)row * KP + col] = (_Float16)(acc[nt][r] + b1v);
        }
    }
}

// ---------------------------------------------------------------------------
// Phase 2: pairwise critic (r6-verified core), tile 32(i) x 64(j), 4i x 2j.
//   s[i][j] = sum_k relu(hy[i,k]+hx[j,k])*w2[k] + b2
//   part[i][jb] = sum_j e^{s};  diag[i] = softplus(s[i][i])
// ---------------------------------------------------------------------------
__device__ void phase_pair(Smem& sm, int bid,
    const unsigned int* __restrict__ hx_h, const unsigned int* __restrict__ hy_h,
    const float* __restrict__ W2, const float* __restrict__ b2,
    float* __restrict__ part, float* __restrict__ diag)
{
    const int tid = threadIdx.x;
    const int jb = bid & 15, ib = bid >> 4;
    const int j0 = jb * 64, i0 = ib * 32;
    const int tx = tid & 31, ty = tid >> 5;

    if (tid < KP2) {
        int k = tid * 2;
        float w0 = (k < LOW) ? W2[k] : 0.f;
        float w1 = (k + 1 < LOW) ? W2[k + 1] : 0.f;
        sm.p.w2s[tid] = pk(w0, w1);
    }

    const int yi = tid >> 3, yq = tid & 7;
    const int xj = tid >> 2, xq = tid & 3;

    const unsigned int* gy = &hy_h[(size_t)(i0 + yi) * KP2 + 2 * yq];
    const unsigned int* gx = &hx_h[(size_t)(j0 + xj) * KP2 + 4 * xq];
    uint2 ga  = *(const uint2*)gy;
    uint2 gb0 = *(const uint2*)gx;
    uint2 gb1 = *(const uint2*)(gx + 2);

    float acc[4][2] = {};
    const h2 hz = h2{(_Float16)0.f, (_Float16)0.f};

    const int NCH = KP2 / 16;                 // 10
    for (int c = 0; c < NCH; ++c) {
        const int buf = c & 1;
        sm.p.Hy[buf][2*yq  ][yi] = ga.x;
        sm.p.Hy[buf][2*yq+1][yi] = ga.y;
        sm.p.Hx[buf][4*xq  ][xj] = gb0.x;
        sm.p.Hx[buf][4*xq+1][xj] = gb0.y;
        sm.p.Hx[buf][4*xq+2][xj] = gb1.x;
        sm.p.Hx[buf][4*xq+3][xj] = gb1.y;
        __syncthreads();
        if (c + 1 < NCH) {
            ga  = *(const uint2*)(gy + (c + 1) * 16);
            gb0 = *(const uint2*)(gx + (c + 1) * 16);
            gb1 = *(const uint2*)(gx + (c + 1) * 16 + 2);
        }
        #pragma unroll
        for (int kk = 0; kk < 16; ++kk) {
            const uint4 ya = *(const uint4*)&sm.p.Hy[buf][kk][ty * 4];
            const uint2 xb = *(const uint2*)&sm.p.Hx[buf][kk][tx * 2];
            const h2 w  = u2h(sm.p.w2s[c * 16 + kk]);
            const h2 x0 = u2h(xb.x), x1 = u2h(xb.y);
            const unsigned int yar[4] = {ya.x, ya.y, ya.z, ya.w};
            #pragma unroll
            for (int r = 0; r < 4; ++r) {
                const h2 a = u2h(yar[r]);
                h2 z0 = __builtin_elementwise_max(a + x0, hz);
                h2 z1 = __builtin_elementwise_max(a + x1, hz);
                acc[r][0] = __builtin_amdgcn_fdot2(z0, w, acc[r][0], false);
                acc[r][1] = __builtin_amdgcn_fdot2(z1, w, acc[r][1], false);
            }
        }
    }

    const float b2v = b2[0];
    #pragma unroll
    for (int r = 0; r < 4; ++r) {
        const int row = i0 + ty * 4 + r;
        float s0 = acc[r][0] + b2v, s1 = acc[r][1] + b2v;
        const int c0 = j0 + tx * 2;
        if (c0 == row)     diag[row] = fmaxf(s0, 0.f) + __logf(1.f + __expf(-fabsf(s0)));
        if (c0 + 1 == row) diag[row] = fmaxf(s1, 0.f) + __logf(1.f + __expf(-fabsf(s1)));
        float es = __expf(s0) + __expf(s1);
        #pragma unroll
        for (int o = 1; o <= 16; o <<= 1) es += __shfl_xor(es, o, 64);
        if (tx == 0) part[(size_t)row * 16 + jb] = es;
    }
}

// ---------------------------------------------------------------------------
// Phase 3: lse per row from 16 partials + global mean. One 256-thr block.
//   lse_i = log(N + sum_jb part[i][jb])   (exp(softplus)=1+e^s identity)
// ---------------------------------------------------------------------------
__device__ void phase_lse(const float* __restrict__ part,
                          const float* __restrict__ diag, float* __restrict__ out)
{
    __shared__ float ssum[4];
    const int tid = threadIdx.x;
    float csum = 0.f;
    #pragma unroll
    for (int g = 0; g < 4; ++g) {
        const int row = g * 256 + tid;
        const float4* p = (const float4*)(part + (size_t)row * 16);
        float s = 0.f;
        #pragma unroll
        for (int q = 0; q < 4; ++q) {
            float4 v = p[q];
            s += (v.x + v.y) + (v.z + v.w);
        }
        csum += diag[row] - __logf((float)N_S + s);
    }
    #pragma unroll
    for (int o = 32; o > 0; o >>= 1) csum += __shfl_xor(csum, o, 64);
    if ((tid & 63) == 0) ssum[tid >> 6] = csum;
    __syncthreads();
    if (tid == 0)
        out[0] = (ssum[0] + ssum[1] + ssum[2] + ssum[3]) * (1.0f / N_S)
               - logf((float)N_S);
}

// ---------------------------------------------------------------------------
__global__ __launch_bounds__(256)
void fused(const float* __restrict__ x, const float* __restrict__ y,
           const float* __restrict__ W1, const float* __restrict__ b1g,
           const float* __restrict__ W2, const float* __restrict__ b2,
           unsigned int* __restrict__ hx_h, unsigned int* __restrict__ hy_h,
           float* __restrict__ part, float* __restrict__ diag,
           float* __restrict__ out)
{
    __shared__ Smem sm;
    cg::grid_group grid = cg::this_grid();
    const int bid = blockIdx.x;

    if (bid < 320)
        phase_gemm(sm, bid, x, y, W1, b1g, hx_h, hy_h);
    grid.sync();
    phase_pair(sm, bid, hx_h, hy_h, W2, b2, part, diag);
    grid.sync();
    if (bid == 0)
        phase_lse(part, diag, out);
}

// --------- fallback path (separate kernels), if coop launch unsupported ----
__global__ __launch_bounds__(256)
void gemm_k(const float* __restrict__ x, const float* __restrict__ y,
            const float* __restrict__ W1, const float* __restrict__ b1g,
            unsigned int* __restrict__ hx_h, unsigned int* __restrict__ hy_h)
{
    __shared__ Smem sm;
    phase_gemm(sm, blockIdx.x, x, y, W1, b1g, hx_h, hy_h);
}
__global__ __launch_bounds__(256)
void pair_k(const unsigned int* __restrict__ hx_h, const unsigned int* __restrict__ hy_h,
            const float* __restrict__ W2, const float* __restrict__ b2,
            float* __restrict__ part, float* __restrict__ diag)
{
    __shared__ Smem sm;
    phase_pair(sm, blockIdx.x, hx_h, hy_h, W2, b2, part, diag);
}
__global__ __launch_bounds__(256)
void lse_k(const float* __restrict__ part, const float* __restrict__ diag,
           float* __restrict__ out)
{
    phase_lse(part, diag, out);
}

// ---------------------------------------------------------------------------
extern "C" void kernel_launch(void* const* d_in, const int* in_sizes, int n_in,
                              void* d_out, int out_size, void* d_ws, size_t ws_size,
                              hipStream_t stream)
{
    const float* x  = (const float*)d_in[0];
    const float* y  = (const float*)d_in[1];
    const float* W1 = (const float*)d_in[2];
    const float* b1 = (const float*)d_in[3];
    const float* W2 = (const float*)d_in[4];
    const float* b2 = (const float*)d_in[5];
    float* outp = (float*)d_out;

    unsigned int* hx_h = (unsigned int*)d_ws;             // N_S*KP2 u32
    unsigned int* hy_h = hx_h + (size_t)N_S * KP2;        // N_S*KP2 u32
    float* part = (float*)(hy_h + (size_t)N_S * KP2);     // N_S*16 f32
    float* diag = part + (size_t)N_S * 16;                // N_S f32

    void* args[] = { (void*)&x, (void*)&y, (void*)&W1, (void*)&b1,
                     (void*)&W2, (void*)&b2, (void*)&hx_h, (void*)&hy_h,
                     (void*)&part, (void*)&diag, (void*)&outp };

    hipError_t err = hipLaunchCooperativeKernel((const void*)fused,
                                                dim3(GRID), dim3(256),
                                                args, 0, stream);
    if (err != hipSuccess) {
        gemm_k<<<320, 256, 0, stream>>>(x, y, W1, b1, hx_h, hy_h);
        pair_k<<<512, 256, 0, stream>>>(hx_h, hy_h, W2, b2, part, diag);
        lse_k<<<1, 256, 0, stream>>>(part, diag, outp);
    }
}

// Round 9
// 40.775 us; speedup vs baseline: 4.0755x; 4.0755x over previous
//
#include <hip/hip_runtime.h>
#include <math.h>

#define N_S 1024
#define XD  768
#define LOW 300
#define KP  320     // f16 k-padding
#define KP2 160     // u32 (h2) per row

typedef _Float16 h2  __attribute__((ext_vector_type(2)));
typedef __fp16   g2  __attribute__((ext_vector_type(2)));
typedef _Float16 v8h __attribute__((ext_vector_type(8)));
typedef float    f4  __attribute__((ext_vector_type(4)));

union U32H2 { unsigned int u; h2 h; };
__device__ inline h2 u2h(unsigned int v){ U32H2 t; t.u = v; return t.h; }
__device__ inline unsigned int pk(float a, float b){
    g2 t = __builtin_amdgcn_cvt_pkrtz(a, b);
    return __builtin_bit_cast(unsigned int, t);
}
union U4V8 { uint4 u; v8h v; };

// ---------------------------------------------------------------------------
// Kernel 1: projection GEMM via MFMA f16 (r8-verified 320-job decomposition).
//   job < 160 : hx[j][k] = sum_m x[j,m]*W1[m,k]
//   job >=160 : hy[i][k] = sum_m y[i,m]*W1[768+m,k] + b1[k]
// Job = 32-row x 64-kcol tile; 256 thr = 4 waves (2M x 2N), K-step 64, dbuf.
// ---------------------------------------------------------------------------
__global__ __launch_bounds__(256)
void gemm_h(const float* __restrict__ x, const float* __restrict__ y,
            const float* __restrict__ W1, const float* __restrict__ b1g,
            unsigned int* __restrict__ hx_h, unsigned int* __restrict__ hy_h)
{
    __shared__ unsigned int As[2][32][34];
    __shared__ unsigned int Bs[2][64][34];

    const int tid = threadIdx.x;
    const int job = blockIdx.x;
    const int which = job >= 160;
    const int t = which ? job - 160 : job;
    const int n0 = (t % 5) * 64;
    const int r0 = (t / 5) * 32;
    const float* A = which ? y : x;
    const float* W = W1 + (size_t)which * XD * LOW;
    _Float16* outh = (_Float16*)(which ? hy_h : hx_h);

    const int w = tid >> 6, l = tid & 63;
    const int wn = w & 1, wm = w >> 1;
    const int lr = l & 15, lg = l >> 4;

    const int arow = tid >> 3, aq = tid & 7;   // A staging: 32 rows x 8 groups
    const int bn = tid & 63, bms = tid >> 6;   // B staging: 64 ncols x 4 m-groups
    const bool bin = (n0 + bn) < LOW;

    f4 acc[2] = {};
    float4 a0, a1; float bw[16];
    a0 = *(const float4*)&A[(size_t)(r0 + arow) * XD + aq * 8];
    a1 = *(const float4*)&A[(size_t)(r0 + arow) * XD + aq * 8 + 4];
    #pragma unroll
    for (int s = 0; s < 16; ++s)
        bw[s] = bin ? W[(size_t)(bms * 16 + s) * LOW + n0 + bn] : 0.f;

    const int NC = XD / 64;                    // 12
    for (int c = 0; c < NC; ++c) {
        const int buf = c & 1;
        *(uint4*)&As[buf][arow][aq * 4] =
            uint4{ pk(a0.x,a0.y), pk(a0.z,a0.w), pk(a1.x,a1.y), pk(a1.z,a1.w) };
        *(uint4*)&Bs[buf][bn][bms * 8] =
            uint4{ pk(bw[0],bw[1]), pk(bw[2],bw[3]), pk(bw[4],bw[5]), pk(bw[6],bw[7]) };
        *(uint4*)&Bs[buf][bn][bms * 8 + 4] =
            uint4{ pk(bw[8],bw[9]), pk(bw[10],bw[11]), pk(bw[12],bw[13]), pk(bw[14],bw[15]) };
        __syncthreads();
        if (c + 1 < NC) {
            const int kb = (c + 1) * 64;
            a0 = *(const float4*)&A[(size_t)(r0 + arow) * XD + kb + aq * 8];
            a1 = *(const float4*)&A[(size_t)(r0 + arow) * XD + kb + aq * 8 + 4];
            #pragma unroll
            for (int s = 0; s < 16; ++s)
                bw[s] = bin ? W[(size_t)(kb + bms * 16 + s) * LOW + n0 + bn] : 0.f;
        }
        #pragma unroll
        for (int ks = 0; ks < 2; ++ks) {
            const int ko = ks * 16 + lg * 4;
            U4V8 af; af.u = *(const uint4*)&As[buf][wm * 16 + lr][ko];
            #pragma unroll
            for (int nt = 0; nt < 2; ++nt) {
                U4V8 bf; bf.u = *(const uint4*)&Bs[buf][wn * 32 + nt * 16 + lr][ko];
                acc[nt] = __builtin_amdgcn_mfma_f32_16x16x32_f16(af.v, bf.v, acc[nt], 0, 0, 0);
            }
        }
    }

    // D: col = l&15, row = 4*(l>>4)+r  (m89-verified)
    #pragma unroll
    for (int nt = 0; nt < 2; ++nt) {
        const int col = n0 + wn * 32 + nt * 16 + lr;
        const float b1v = (which && col < LOW) ? b1g[col] : 0.f;
        #pragma unroll
        for (int r = 0; r < 4; ++r) {
            const int row = r0 + wm * 16 + lg * 4 + r;
            outh[(size_t)row * KP + col] = (_Float16)(acc[nt][r] + b1v);
        }
    }
}

// ---------------------------------------------------------------------------
// Kernel 2: pairwise critic, 4i x 4j x half-k per thread, single-stage LDS.
//   s[i][j] = sum_k relu(hy[i,k]+hx[j,k])*w2[k] + b2
//   part[i][jb] = sum_{j in block} e^s;  diag[i] = softplus(s[i][i])
// Tile 32(i) x 64(j), 256 thr, 512 blocks (2/CU, 8 waves/CU).
// Lane mapping: tx=tid&15 (4j), kh=(tid>>4)&1 (k-half), iy=tid>>5 (4i).
// Whole K staged once (64.6 KB LDS), one barrier; k-halves combined with
// one shfl_xor(16) inside the wave.
// ---------------------------------------------------------------------------
__global__ __launch_bounds__(256)
void pair_kernel(const unsigned int* __restrict__ hx_h, const unsigned int* __restrict__ hy_h,
                 const float* __restrict__ W2, const float* __restrict__ b2,
                 float* __restrict__ part, float* __restrict__ diag)
{
    const int jb = blockIdx.x, ib = blockIdx.y;
    const int j0 = jb * 64, i0 = ib * 32;

    __shared__ unsigned int Hy[160][34];   // [kk][i]
    __shared__ unsigned int Hx[160][66];   // [kk][j]
    __shared__ unsigned int w2s[KP2];

    const int tid = threadIdx.x;

    // ---- stage Hy: transpose [i][kk] -> [kk][i] ----
    {
        const int r = tid >> 3, q = tid & 7;            // r 0..31, q 0..7
        const unsigned int* src = &hy_h[(size_t)(i0 + r) * KP2];
        #pragma unroll
        for (int e = 0; e < 5; ++e) {
            const int k4 = q + 8 * e;                   // uint4 idx 0..39
            uint4 v = *(const uint4*)&src[k4 * 4];
            Hy[k4*4+0][r] = v.x; Hy[k4*4+1][r] = v.y;
            Hy[k4*4+2][r] = v.z; Hy[k4*4+3][r] = v.w;
        }
    }
    // ---- stage Hx ----
    {
        const int r = tid >> 2, q = tid & 3;            // r 0..63, q 0..3
        const unsigned int* src = &hx_h[(size_t)(j0 + r) * KP2];
        #pragma unroll
        for (int e = 0; e < 10; ++e) {
            const int k4 = q + 4 * e;                   // 0..39
            uint4 v = *(const uint4*)&src[k4 * 4];
            Hx[k4*4+0][r] = v.x; Hx[k4*4+1][r] = v.y;
            Hx[k4*4+2][r] = v.z; Hx[k4*4+3][r] = v.w;
        }
    }
    if (tid < KP2) {
        int k = tid * 2;
        float w0 = (k < LOW) ? W2[k] : 0.f;
        float w1 = (k + 1 < LOW) ? W2[k + 1] : 0.f;
        w2s[tid] = pk(w0, w1);
    }
    __syncthreads();

    const int tx = tid & 15;           // j = j0 + tx*4 + q
    const int kh = (tid >> 4) & 1;     // k-half (partner lane = lane^16)
    const int iy = tid >> 5;           // i = i0 + iy*4 + r

    float acc[4][4] = {};              // [r][q]
    const h2 hz = h2{(_Float16)0.f, (_Float16)0.f};
    const int kbase = kh * 80;

    #pragma unroll 4
    for (int kki = 0; kki < 80; ++kki) {
        const int kk = kbase + kki;
        const uint4 ya = *(const uint4*)&Hy[kk][iy * 4];
        const uint4 xb = *(const uint4*)&Hx[kk][tx * 4];
        const h2 w = u2h(w2s[kk]);
        const unsigned int yar[4] = {ya.x, ya.y, ya.z, ya.w};
        const unsigned int xbr[4] = {xb.x, xb.y, xb.z, xb.w};
        #pragma unroll
        for (int r = 0; r < 4; ++r) {
            const h2 a = u2h(yar[r]);
            #pragma unroll
            for (int q = 0; q < 4; ++q) {
                h2 z = __builtin_elementwise_max(a + u2h(xbr[q]), hz);
                acc[r][q] = __builtin_amdgcn_fdot2(z, w, acc[r][q], false);
            }
        }
    }

    // combine the two k-halves: partner lane differs only in bit 4
    #pragma unroll
    for (int r = 0; r < 4; ++r)
        #pragma unroll
        for (int q = 0; q < 4; ++q)
            acc[r][q] += __shfl_xor(acc[r][q], 16, 64);

    const float b2v = b2[0];
    #pragma unroll
    for (int r = 0; r < 4; ++r) {
        const int row = i0 + iy * 4 + r;
        float es = 0.f;
        #pragma unroll
        for (int q = 0; q < 4; ++q) {
            const float s = acc[r][q] + b2v;
            es += __expf(s);
            const int col = j0 + tx * 4 + q;
            if (col == row)
                diag[row] = fmaxf(s, 0.f) + __logf(1.f + __expf(-fabsf(s)));
        }
        #pragma unroll
        for (int o = 1; o <= 8; o <<= 1) es += __shfl_xor(es, o, 64);
        if ((tid & 31) == 0) part[(size_t)row * 16 + jb] = es;
    }
}

// ---------------------------------------------------------------------------
// Kernel 3: per-row lse from 16 partials + global mean. One 256-thr block.
//   lse_i = log(N + sum_jb part[i][jb])   (exp(softplus)=1+e^s identity)
// ---------------------------------------------------------------------------
__global__ __launch_bounds__(256)
void lse_final(const float* __restrict__ part, const float* __restrict__ diag,
               float* __restrict__ out)
{
    __shared__ float ssum[4];
    const int tid = threadIdx.x;
    float csum = 0.f;
    #pragma unroll
    for (int g = 0; g < 4; ++g) {
        const int row = g * 256 + tid;
        const float4* p = (const float4*)(part + (size_t)row * 16);
        float s = 0.f;
        #pragma unroll
        for (int q = 0; q < 4; ++q) {
            float4 v = p[q];
            s += (v.x + v.y) + (v.z + v.w);
        }
        csum += diag[row] - __logf((float)N_S + s);
    }
    #pragma unroll
    for (int o = 32; o > 0; o >>= 1) csum += __shfl_xor(csum, o, 64);
    if ((tid & 63) == 0) ssum[tid >> 6] = csum;
    __syncthreads();
    if (tid == 0)
        out[0] = (ssum[0] + ssum[1] + ssum[2] + ssum[3]) * (1.0f / N_S)
               - logf((float)N_S);
}

// ---------------------------------------------------------------------------
extern "C" void kernel_launch(void* const* d_in, const int* in_sizes, int n_in,
                              void* d_out, int out_size, void* d_ws, size_t ws_size,
                              hipStream_t stream)
{
    const float* x  = (const float*)d_in[0];
    const float* y  = (const float*)d_in[1];
    const float* W1 = (const float*)d_in[2];
    const float* b1 = (const float*)d_in[3];
    const float* W2 = (const float*)d_in[4];
    const float* b2 = (const float*)d_in[5];
    float* outp = (float*)d_out;

    unsigned int* hx_h = (unsigned int*)d_ws;             // N_S*KP2 u32
    unsigned int* hy_h = hx_h + (size_t)N_S * KP2;        // N_S*KP2 u32
    float* part = (float*)(hy_h + (size_t)N_S * KP2);     // N_S*16 f32
    float* diag = part + (size_t)N_S * 16;                // N_S f32

    gemm_h<<<320, 256, 0, stream>>>(x, y, W1, b1, hx_h, hy_h);

    dim3 g2(16, 32);                      // j-tiles, i-tiles
    pair_kernel<<<g2, 256, 0, stream>>>(hx_h, hy_h, W2, b2, part, diag);

    lse_final<<<1, 256, 0, stream>>>(part, diag, outp);
}